// Round 8
// baseline (229.698 us; speedup 1.0000x reference)
//
#include <hip/hip_runtime.h>

typedef float f32x4 __attribute__((ext_vector_type(4)));
typedef short s16x8 __attribute__((ext_vector_type(8)));

#define NN 2048
#define FIN 512
#define FOUT 256
#define L2E 1.4426950408889634f

__device__ __forceinline__ unsigned short f2bf(float f) {
  unsigned u = __builtin_bit_cast(unsigned, f);
  u += 0x7fffu + ((u >> 16) & 1u);
  return (unsigned short)(u >> 16);
}

__device__ __forceinline__ unsigned pkbf(float lo, float hi) {
  unsigned r;
  asm("v_cvt_pk_bf16_f32 %0, %1, %2" : "=v"(r) : "v"(lo), "v"(hi));
  return r;
}

// guaranteed single-instruction 2^x
__device__ __forceinline__ float exp2a(float x) {
  float r;
  asm("v_exp_f32 %0, %1" : "=v"(r) : "v"(x));
  return r;
}

// ---------------- kernel 1: v1 = W @ (ht @ a1), v2 = W @ (ht @ a2) ----------------
// (r7-proven) Grid 128 x 256thr; each wave handles one column c, single reduce chain.
__global__ __launch_bounds__(256) void prep_vecs_k(const float* __restrict__ W,
                                                   const float* __restrict__ HT,
                                                   const float* __restrict__ A,
                                                   float* __restrict__ v1,
                                                   float* __restrict__ v2) {
  __shared__ __align__(16) float w1[256];
  __shared__ __align__(16) float w2[256];
  int t = threadIdx.x;
  {
    float s1 = 0.f, s2 = 0.f;
    for (int k = 0; k < 64; k++) {
      float h = HT[t * 64 + k];
      s1 += h * A[k];
      s2 += h * A[64 + k];
    }
    w1[t] = s1;
    w2[t] = s2;
  }
  __syncthreads();
  int wv = t >> 6, l = t & 63;
  int c = blockIdx.x * 4 + wv;
  float4 u1 = *(const float4*)(w1 + l * 4);
  float4 u2 = *(const float4*)(w2 + l * 4);
  float4 x = *(const float4*)(W + (size_t)c * FOUT + l * 4);
  float a1 = x.x * u1.x + x.y * u1.y + x.z * u1.z + x.w * u1.w;
  float a2 = x.x * u2.x + x.y * u2.y + x.z * u2.z + x.w * u2.w;
  for (int o = 32; o; o >>= 1) {
    a1 += __shfl_xor(a1, o);
    a2 += __shfl_xor(a2, o);
  }
  if (l == 0) {
    v1[c] = a1;
    v2[c] = a2;
  }
}

// ---------------- kernel 2: wT[f][c] = bf16(W[c][f]) (r7-proven) ----------------
__global__ void prep_wT_k(const float* __restrict__ W, unsigned short* __restrict__ wT) {
  int id = blockIdx.x * 256 + threadIdx.x;  // 131072 total
  int f = id >> 9, c = id & 511;
  wT[id] = f2bf(W[c * FOUT + f]);
}

// ---------------- kernel 2b: adj bit-compress (r5/r7-proven) ----------------
__global__ __launch_bounds__(512) void compress_k(const int* __restrict__ adj,
                                                  unsigned* __restrict__ bits) {
  int ct = blockIdx.x * 512 + threadIdx.x;  // 0..524287
  const int4* src = (const int4*)adj + (size_t)ct * 16;
  unsigned w0 = 0u, w1 = 0u;
#pragma unroll
  for (int k = 0; k < 8; k++) {
    int4 a = src[k];
    unsigned nib = (unsigned)(a.x > 0) | ((unsigned)(a.y > 0) << 1) |
                   ((unsigned)(a.z > 0) << 2) | ((unsigned)(a.w > 0) << 3);
    w0 |= nib << (k * 4);
  }
#pragma unroll
  for (int k = 0; k < 8; k++) {
    int4 a = src[8 + k];
    unsigned nib = (unsigned)(a.x > 0) | ((unsigned)(a.y > 0) << 1) |
                   ((unsigned)(a.z > 0) << 2) | ((unsigned)(a.w > 0) << 3);
    w1 |= nib << (k * 4);
  }
  uint2 o;
  o.x = w0;
  o.y = w1;
  *(uint2*)(bits + (size_t)ct * 2) = o;
}

// ---------------- kernel 3: hT = (X @ W)^T bf16 via MFMA (r5/r7-proven, verbatim) --
__global__ __launch_bounds__(512) void gemm1_k(const float* __restrict__ inp,
                                               const unsigned short* __restrict__ wT,
                                               unsigned short* __restrict__ hT,
                                               const float* __restrict__ v1,
                                               const float* __restrict__ v2,
                                               float* __restrict__ f1,
                                               float* __restrict__ f2) {
  int tid = threadIdx.x;
  int w = tid >> 6, l = tid & 63, lr = l & 15, lg = l >> 4;
  int jtile = blockIdx.x * 64;  // global row base (0..16384)
  f32x4 acc[2][4] = {};
  float s1[4] = {0.f, 0.f, 0.f, 0.f}, s2[4] = {0.f, 0.f, 0.f, 0.f};
  for (int c0 = 0; c0 < FIN; c0 += 32) {
    s16x8 af[2];
#pragma unroll
    for (int mf = 0; mf < 2; mf++) {
      int f = w * 32 + mf * 16 + lr;
      af[mf] = *(const s16x8*)(wT + (size_t)f * FIN + c0 + lg * 8);
    }
    float4 va0, va1, vb0, vb1;
    if (w == 0) {
      va0 = *(const float4*)(v1 + c0 + lg * 8);
      va1 = *(const float4*)(v1 + c0 + lg * 8 + 4);
      vb0 = *(const float4*)(v2 + c0 + lg * 8);
      vb1 = *(const float4*)(v2 + c0 + lg * 8 + 4);
    }
    s16x8 bfv[4];
#pragma unroll
    for (int nf = 0; nf < 4; nf++) {
      int jg = jtile + nf * 16 + lr;
      const float* p = inp + (size_t)jg * FIN + c0 + lg * 8;
      float4 x0 = *(const float4*)p;
      float4 x1 = *(const float4*)(p + 4);
      s16x8 t;
      t[0] = (short)f2bf(x0.x); t[1] = (short)f2bf(x0.y);
      t[2] = (short)f2bf(x0.z); t[3] = (short)f2bf(x0.w);
      t[4] = (short)f2bf(x1.x); t[5] = (short)f2bf(x1.y);
      t[6] = (short)f2bf(x1.z); t[7] = (short)f2bf(x1.w);
      bfv[nf] = t;
      if (w == 0) {
        s1[nf] += x0.x * va0.x + x0.y * va0.y + x0.z * va0.z + x0.w * va0.w +
                  x1.x * va1.x + x1.y * va1.y + x1.z * va1.z + x1.w * va1.w;
        s2[nf] += x0.x * vb0.x + x0.y * vb0.y + x0.z * vb0.z + x0.w * vb0.w +
                  x1.x * vb1.x + x1.y * vb1.y + x1.z * vb1.z + x1.w * vb1.w;
      }
    }
#pragma unroll
    for (int mf = 0; mf < 2; mf++)
#pragma unroll
      for (int nf = 0; nf < 4; nf++)
        acc[mf][nf] =
            __builtin_amdgcn_mfma_f32_16x16x32_bf16(af[mf], bfv[nf], acc[mf][nf], 0, 0, 0);
  }
  int bb = jtile >> 11, jl = jtile & 2047;
#pragma unroll
  for (int mf = 0; mf < 2; mf++)
#pragma unroll
    for (int nf = 0; nf < 4; nf++)
#pragma unroll
      for (int r = 0; r < 4; r++) {
        int f = w * 32 + mf * 16 + lg * 4 + r;
        int j = jl + nf * 16 + lr;
        hT[((size_t)bb * FOUT + f) * (size_t)NN + j] = f2bf(acc[mf][nf][r]);
      }
  if (w == 0) {
#pragma unroll
    for (int nf = 0; nf < 4; nf++) {
      float a = s1[nf], b = s2[nf];
      a += __shfl_xor(a, 16); a += __shfl_xor(a, 32);
      b += __shfl_xor(b, 16); b += __shfl_xor(b, 32);
      if (lg == 0) {
        int jg = jtile + nf * 16 + lr;
        f1[jg] = a * L2E;
        f2[jg] = b * L2E;
      }
    }
  }
}

// ---------------- kernel 4: barrier-free fused masked-softmax + PV + ELU -----------
// NEW geometry: 16 i-rows x 256 f per block (4 waves x 64 f), grid 1024 ->
// 4 blocks/CU x 4 waves = 4 waves/SIMD. No LDS, no barriers, linear b mapping.
// ls via ones-column MFMA (accs[r] = rowsum, no shuffles). Mask/prefetch pattern
// byte-identical to the r7-proven path.
__global__ __launch_bounds__(256, 4) void pv_k(const unsigned* __restrict__ bits,
                                               const unsigned short* __restrict__ hT,
                                               const float* __restrict__ f1,
                                               const float* __restrict__ f2,
                                               float* __restrict__ out) {
  int tid = threadIdx.x;
  int w = tid >> 6;  // f-slice 0..3
  int l = tid & 63, lr = l & 15, lg = l >> 4;
  int blk = blockIdx.x;       // 1024
  int b = blk >> 7;           // batch 0..7
  int i0 = (blk & 127) * 16;  // row tile
  int f0 = w * 64;
  int ja = lg * 8;

  const unsigned* brow = bits + ((size_t)(b * NN + i0 + lr)) * 64;
  const unsigned short* hp_base = hT + ((size_t)b * FOUT + f0 + lr) * NN + ja;
  const float* f2b = f2 + b * NN + ja;
  float fi = f1[b * NN + i0 + lr];
  unsigned sh = (unsigned)(lg * 8);

  f32x4 acc0 = {}, acc1 = {}, acc2 = {}, acc3 = {}, accs = {};
  s16x8 ones;
#pragma unroll
  for (int e = 0; e < 8; e++) ones[e] = (short)0x3F80;  // bf16 1.0

  auto pcompb = [&](unsigned byt, const float4& fA, const float4& fB) -> s16x8 {
    float e0 = fi + fA.x, e1 = fi + fA.y, e2 = fi + fA.z, e3 = fi + fA.w;
    float e4 = fi + fB.x, e5 = fi + fB.y, e6 = fi + fB.z, e7 = fi + fB.w;
    e0 = fmaxf(e0, 0.2f * e0); e1 = fmaxf(e1, 0.2f * e1);
    e2 = fmaxf(e2, 0.2f * e2); e3 = fmaxf(e3, 0.2f * e3);
    e4 = fmaxf(e4, 0.2f * e4); e5 = fmaxf(e5, 0.2f * e5);
    e6 = fmaxf(e6, 0.2f * e6); e7 = fmaxf(e7, 0.2f * e7);
    float p0 = (byt & 1u)   ? exp2a(e0) : 0.f;
    float p1 = (byt & 2u)   ? exp2a(e1) : 0.f;
    float p2 = (byt & 4u)   ? exp2a(e2) : 0.f;
    float p3 = (byt & 8u)   ? exp2a(e3) : 0.f;
    float p4 = (byt & 16u)  ? exp2a(e4) : 0.f;
    float p5 = (byt & 32u)  ? exp2a(e5) : 0.f;
    float p6 = (byt & 64u)  ? exp2a(e6) : 0.f;
    float p7 = (byt & 128u) ? exp2a(e7) : 0.f;
    union { unsigned u[4]; s16x8 v; } pk;
    pk.u[0] = pkbf(p0, p1); pk.u[1] = pkbf(p2, p3);
    pk.u[2] = pkbf(p4, p5); pk.u[3] = pkbf(p6, p7);
    return pk.v;
  };

  // prefetched state: B-frags + f2 for substep j0=0; bit-words for j in [0,128)
  s16x8 pb0 = *(const s16x8*)(hp_base);
  s16x8 pb1 = *(const s16x8*)(hp_base + 16 * NN);
  s16x8 pb2 = *(const s16x8*)(hp_base + 32 * NN);
  s16x8 pb3 = *(const s16x8*)(hp_base + 48 * NN);
  float4 pfA = *(const float4*)(f2b);
  float4 pfB = *(const float4*)(f2b + 4);
  uint4 q = *(const uint4*)(brow);

  for (int jb = 0; jb < NN; jb += 128) {
    uint4 c = q;
    if (jb + 128 < NN) q = *(const uint4*)(brow + (jb >> 5) + 4);
#pragma unroll
    for (int s = 0; s < 4; s++) {
      int j0 = jb + s * 32;
      unsigned wd = (s == 0) ? c.x : (s == 1) ? c.y : (s == 2) ? c.z : c.w;
      s16x8 cb0 = pb0, cb1 = pb1, cb2 = pb2, cb3 = pb3;
      float4 cfA = pfA, cfB = pfB;
      if (j0 + 32 < NN) {
        const unsigned short* hp = hp_base + j0 + 32;
        pb0 = *(const s16x8*)(hp);
        pb1 = *(const s16x8*)(hp + 16 * NN);
        pb2 = *(const s16x8*)(hp + 32 * NN);
        pb3 = *(const s16x8*)(hp + 48 * NN);
        pfA = *(const float4*)(f2b + j0 + 32);
        pfB = *(const float4*)(f2b + j0 + 36);
      }
      s16x8 af = pcompb((wd >> sh) & 0xffu, cfA, cfB);
      acc0 = __builtin_amdgcn_mfma_f32_16x16x32_bf16(af, cb0, acc0, 0, 0, 0);
      acc1 = __builtin_amdgcn_mfma_f32_16x16x32_bf16(af, cb1, acc1, 0, 0, 0);
      acc2 = __builtin_amdgcn_mfma_f32_16x16x32_bf16(af, cb2, acc2, 0, 0, 0);
      acc3 = __builtin_amdgcn_mfma_f32_16x16x32_bf16(af, cb3, acc3, 0, 0, 0);
      accs = __builtin_amdgcn_mfma_f32_16x16x32_bf16(af, ones, accs, 0, 0, 0);
    }
  }

  // accs[r] = rowsum(row = lg*4 + r), replicated across all n -> no shuffles
  float rd[4];
#pragma unroll
  for (int r = 0; r < 4; r++) rd[r] = 1.0f / accs[r];

  auto wr = [&](const f32x4& a, int nf) {
#pragma unroll
    for (int r = 0; r < 4; r++) {
      float v = a[r] * rd[r];
      v = (v > 0.f) ? v : expm1f(v);
      out[((size_t)(b * NN + i0 + lg * 4 + r)) * FOUT + f0 + nf * 16 + lr] = v;
    }
  };
  wr(acc0, 0); wr(acc1, 1); wr(acc2, 2); wr(acc3, 3);
}

extern "C" void kernel_launch(void* const* d_in, const int* in_sizes, int n_in,
                              void* d_out, int out_size, void* d_ws, size_t ws_size,
                              hipStream_t stream) {
  const float* inp = (const float*)d_in[0];   // [8][2048][512] f32
  const int* adj   = (const int*)d_in[1];     // [8][2048][2048] i32
  const float* W   = (const float*)d_in[2];   // [512][256] f32
  const float* HT  = (const float*)d_in[3];   // [256][64] f32
  const float* A   = (const float*)d_in[4];   // [128][1] f32
  float* out = (float*)d_out;                 // [8][2048][256] f32

  char* ws = (char*)d_ws;
  float* v1 = (float*)ws;                              // 512 f32
  float* v2 = v1 + 512;                                // 512 f32
  float* f1 = (float*)(ws + 4096);                     // 16384 f32 (x log2e)
  float* f2 = (float*)(ws + 69632);                    // 16384 f32 (x log2e)
  unsigned short* wT = (unsigned short*)(ws + 135168); // 256x512 bf16
  unsigned short* hT = (unsigned short*)(ws + 397312); // 8x256x2048 bf16 -> end 8785920
  unsigned* bits = (unsigned*)(ws + 8785920);          // 8x2048x64 u32  -> end 12980224

  hipLaunchKernelGGL(prep_vecs_k, dim3(128), dim3(256), 0, stream, W, HT, A, v1, v2);
  hipLaunchKernelGGL(prep_wT_k, dim3(512), dim3(256), 0, stream, W, wT);
  hipLaunchKernelGGL(compress_k, dim3(1024), dim3(512), 0, stream, adj, bits);
  hipLaunchKernelGGL(gemm1_k, dim3(256), dim3(512), 0, stream, inp, wT, hT, v1, v2, f1,
                     f2);
  hipLaunchKernelGGL(pv_k, dim3(1024), dim3(256), 0, stream, bits, hT, f1, f2, out);
}

// Round 9
// 171.395 us; speedup vs baseline: 1.3402x; 1.3402x over previous
//
#include <hip/hip_runtime.h>

typedef float f32x4 __attribute__((ext_vector_type(4)));
typedef short s16x8 __attribute__((ext_vector_type(8)));

#define NN 2048
#define FIN 512
#define FOUT 256
#define L2E 1.4426950408889634f

__device__ __forceinline__ unsigned short f2bf(float f) {
  unsigned u = __builtin_bit_cast(unsigned, f);
  u += 0x7fffu + ((u >> 16) & 1u);
  return (unsigned short)(u >> 16);
}

__device__ __forceinline__ unsigned pkbf(float lo, float hi) {
  unsigned r;
  asm("v_cvt_pk_bf16_f32 %0, %1, %2" : "=v"(r) : "v"(lo), "v"(hi));
  return r;
}

// guaranteed single-instruction 2^x
__device__ __forceinline__ float exp2a(float x) {
  float r;
  asm("v_exp_f32 %0, %1" : "=v"(r) : "v"(x));
  return r;
}

// ---------------- kernel 1: v1 = W @ (ht @ a1), v2 = W @ (ht @ a2) ----------------
// (r7-proven) Grid 128 x 256thr; each wave handles one column c, single reduce chain.
__global__ __launch_bounds__(256) void prep_vecs_k(const float* __restrict__ W,
                                                   const float* __restrict__ HT,
                                                   const float* __restrict__ A,
                                                   float* __restrict__ v1,
                                                   float* __restrict__ v2) {
  __shared__ __align__(16) float w1[256];
  __shared__ __align__(16) float w2[256];
  int t = threadIdx.x;
  {
    float s1 = 0.f, s2 = 0.f;
    for (int k = 0; k < 64; k++) {
      float h = HT[t * 64 + k];
      s1 += h * A[k];
      s2 += h * A[64 + k];
    }
    w1[t] = s1;
    w2[t] = s2;
  }
  __syncthreads();
  int wv = t >> 6, l = t & 63;
  int c = blockIdx.x * 4 + wv;
  float4 u1 = *(const float4*)(w1 + l * 4);
  float4 u2 = *(const float4*)(w2 + l * 4);
  float4 x = *(const float4*)(W + (size_t)c * FOUT + l * 4);
  float a1 = x.x * u1.x + x.y * u1.y + x.z * u1.z + x.w * u1.w;
  float a2 = x.x * u2.x + x.y * u2.y + x.z * u2.z + x.w * u2.w;
  for (int o = 32; o; o >>= 1) {
    a1 += __shfl_xor(a1, o);
    a2 += __shfl_xor(a2, o);
  }
  if (l == 0) {
    v1[c] = a1;
    v2[c] = a2;
  }
}

// ---------------- kernel 2: wT[f][c] = bf16(W[c][f]) (r7-proven) ----------------
__global__ void prep_wT_k(const float* __restrict__ W, unsigned short* __restrict__ wT) {
  int id = blockIdx.x * 256 + threadIdx.x;  // 131072 total
  int f = id >> 9, c = id & 511;
  wT[id] = f2bf(W[c * FOUT + f]);
}

// ---------------- kernel 2b: adj bit-compress (r5/r7-proven) ----------------
__global__ __launch_bounds__(512) void compress_k(const int* __restrict__ adj,
                                                  unsigned* __restrict__ bits) {
  int ct = blockIdx.x * 512 + threadIdx.x;  // 0..524287
  const int4* src = (const int4*)adj + (size_t)ct * 16;
  unsigned w0 = 0u, w1 = 0u;
#pragma unroll
  for (int k = 0; k < 8; k++) {
    int4 a = src[k];
    unsigned nib = (unsigned)(a.x > 0) | ((unsigned)(a.y > 0) << 1) |
                   ((unsigned)(a.z > 0) << 2) | ((unsigned)(a.w > 0) << 3);
    w0 |= nib << (k * 4);
  }
#pragma unroll
  for (int k = 0; k < 8; k++) {
    int4 a = src[8 + k];
    unsigned nib = (unsigned)(a.x > 0) | ((unsigned)(a.y > 0) << 1) |
                   ((unsigned)(a.z > 0) << 2) | ((unsigned)(a.w > 0) << 3);
    w1 |= nib << (k * 4);
  }
  uint2 o;
  o.x = w0;
  o.y = w1;
  *(uint2*)(bits + (size_t)ct * 2) = o;
}

// ---------------- kernel 3: hT = (X @ W)^T bf16 via MFMA (r5/r7-proven, verbatim) --
__global__ __launch_bounds__(512) void gemm1_k(const float* __restrict__ inp,
                                               const unsigned short* __restrict__ wT,
                                               unsigned short* __restrict__ hT,
                                               const float* __restrict__ v1,
                                               const float* __restrict__ v2,
                                               float* __restrict__ f1,
                                               float* __restrict__ f2) {
  int tid = threadIdx.x;
  int w = tid >> 6, l = tid & 63, lr = l & 15, lg = l >> 4;
  int jtile = blockIdx.x * 64;  // global row base (0..16384)
  f32x4 acc[2][4] = {};
  float s1[4] = {0.f, 0.f, 0.f, 0.f}, s2[4] = {0.f, 0.f, 0.f, 0.f};
  for (int c0 = 0; c0 < FIN; c0 += 32) {
    s16x8 af[2];
#pragma unroll
    for (int mf = 0; mf < 2; mf++) {
      int f = w * 32 + mf * 16 + lr;
      af[mf] = *(const s16x8*)(wT + (size_t)f * FIN + c0 + lg * 8);
    }
    float4 va0, va1, vb0, vb1;
    if (w == 0) {
      va0 = *(const float4*)(v1 + c0 + lg * 8);
      va1 = *(const float4*)(v1 + c0 + lg * 8 + 4);
      vb0 = *(const float4*)(v2 + c0 + lg * 8);
      vb1 = *(const float4*)(v2 + c0 + lg * 8 + 4);
    }
    s16x8 bfv[4];
#pragma unroll
    for (int nf = 0; nf < 4; nf++) {
      int jg = jtile + nf * 16 + lr;
      const float* p = inp + (size_t)jg * FIN + c0 + lg * 8;
      float4 x0 = *(const float4*)p;
      float4 x1 = *(const float4*)(p + 4);
      s16x8 t;
      t[0] = (short)f2bf(x0.x); t[1] = (short)f2bf(x0.y);
      t[2] = (short)f2bf(x0.z); t[3] = (short)f2bf(x0.w);
      t[4] = (short)f2bf(x1.x); t[5] = (short)f2bf(x1.y);
      t[6] = (short)f2bf(x1.z); t[7] = (short)f2bf(x1.w);
      bfv[nf] = t;
      if (w == 0) {
        s1[nf] += x0.x * va0.x + x0.y * va0.y + x0.z * va0.z + x0.w * va0.w +
                  x1.x * va1.x + x1.y * va1.y + x1.z * va1.z + x1.w * va1.w;
        s2[nf] += x0.x * vb0.x + x0.y * vb0.y + x0.z * vb0.z + x0.w * vb0.w +
                  x1.x * vb1.x + x1.y * vb1.y + x1.z * vb1.z + x1.w * vb1.w;
      }
    }
#pragma unroll
    for (int mf = 0; mf < 2; mf++)
#pragma unroll
      for (int nf = 0; nf < 4; nf++)
        acc[mf][nf] =
            __builtin_amdgcn_mfma_f32_16x16x32_bf16(af[mf], bfv[nf], acc[mf][nf], 0, 0, 0);
  }
  int bb = jtile >> 11, jl = jtile & 2047;
#pragma unroll
  for (int mf = 0; mf < 2; mf++)
#pragma unroll
    for (int nf = 0; nf < 4; nf++)
#pragma unroll
      for (int r = 0; r < 4; r++) {
        int f = w * 32 + mf * 16 + lg * 4 + r;
        int j = jl + nf * 16 + lr;
        hT[((size_t)bb * FOUT + f) * (size_t)NN + j] = f2bf(acc[mf][nf][r]);
      }
  if (w == 0) {
#pragma unroll
    for (int nf = 0; nf < 4; nf++) {
      float a = s1[nf], b = s2[nf];
      a += __shfl_xor(a, 16); a += __shfl_xor(a, 32);
      b += __shfl_xor(b, 16); b += __shfl_xor(b, 32);
      if (lg == 0) {
        int jg = jtile + nf * 16 + lr;
        f1[jg] = a * L2E;
        f2[jg] = b * L2E;
      }
    }
  }
}

// ---------------- kernel 4: barrier-free fused masked-softmax + PV + ELU -----------
// r7-proven 32-row frame (32 i-rows x 64 f per wave, grid 512, no LDS, no barriers,
// depth-1 B-frag prefetch) with TWO deltas:
//  (a) b = blk & 7  -> batch == XCD (round-robin dispatch): per-XCD working set
//      1 MB hT + 0.5 MB bits fits the 4 MB L2 (was 12 MB thrash with linear map).
//  (b) ls via ones-column MFMA (r8-proven): no per-substep adds, no shuffle epilogue.
__global__ __launch_bounds__(256, 2) void pv_k(const unsigned* __restrict__ bits,
                                               const unsigned short* __restrict__ hT,
                                               const float* __restrict__ f1,
                                               const float* __restrict__ f2,
                                               float* __restrict__ out) {
  int tid = threadIdx.x;
  int w = tid >> 6;  // f-slice 0..3
  int l = tid & 63, lr = l & 15, lg = l >> 4;
  int blk = blockIdx.x;       // 512
  int b = blk & 7;            // batch == XCD
  int i0 = (blk >> 3) * 32;   // 64 row-tiles per batch
  int f0 = w * 64;
  int ja = lg * 8;

  const unsigned* brow0 = bits + ((size_t)(b * NN + i0 + lr)) * 64;
  const unsigned* brow1 = brow0 + 16 * 64;
  const unsigned short* hp_base = hT + ((size_t)b * FOUT + f0 + lr) * NN + ja;
  const float* f2b = f2 + b * NN + ja;
  float fi0 = f1[b * NN + i0 + lr];
  float fi1 = f1[b * NN + i0 + 16 + lr];
  unsigned sh = (unsigned)(lg * 8);

  f32x4 acc[2][4] = {};
  f32x4 accs0 = {}, accs1 = {};
  s16x8 ones;
#pragma unroll
  for (int e = 0; e < 8; e++) ones[e] = (short)0x3F80;  // bf16 1.0

  auto pcompb = [&](float fi, unsigned byt, const float4& fA, const float4& fB) -> s16x8 {
    float e0 = fi + fA.x, e1 = fi + fA.y, e2 = fi + fA.z, e3 = fi + fA.w;
    float e4 = fi + fB.x, e5 = fi + fB.y, e6 = fi + fB.z, e7 = fi + fB.w;
    e0 = fmaxf(e0, 0.2f * e0); e1 = fmaxf(e1, 0.2f * e1);
    e2 = fmaxf(e2, 0.2f * e2); e3 = fmaxf(e3, 0.2f * e3);
    e4 = fmaxf(e4, 0.2f * e4); e5 = fmaxf(e5, 0.2f * e5);
    e6 = fmaxf(e6, 0.2f * e6); e7 = fmaxf(e7, 0.2f * e7);
    float p0 = (byt & 1u)   ? exp2a(e0) : 0.f;
    float p1 = (byt & 2u)   ? exp2a(e1) : 0.f;
    float p2 = (byt & 4u)   ? exp2a(e2) : 0.f;
    float p3 = (byt & 8u)   ? exp2a(e3) : 0.f;
    float p4 = (byt & 16u)  ? exp2a(e4) : 0.f;
    float p5 = (byt & 32u)  ? exp2a(e5) : 0.f;
    float p6 = (byt & 64u)  ? exp2a(e6) : 0.f;
    float p7 = (byt & 128u) ? exp2a(e7) : 0.f;
    union { unsigned u[4]; s16x8 v; } pk;
    pk.u[0] = pkbf(p0, p1); pk.u[1] = pkbf(p2, p3);
    pk.u[2] = pkbf(p4, p5); pk.u[3] = pkbf(p6, p7);
    return pk.v;
  };

  // prefetched state: B-frags + f2 for substep j0=0; bit-words for j in [0,128)
  s16x8 pb0 = *(const s16x8*)(hp_base);
  s16x8 pb1 = *(const s16x8*)(hp_base + 16 * NN);
  s16x8 pb2 = *(const s16x8*)(hp_base + 32 * NN);
  s16x8 pb3 = *(const s16x8*)(hp_base + 48 * NN);
  float4 pfA = *(const float4*)(f2b);
  float4 pfB = *(const float4*)(f2b + 4);
  uint4 q0 = *(const uint4*)(brow0);
  uint4 q1 = *(const uint4*)(brow1);

  for (int jb = 0; jb < NN; jb += 128) {
    uint4 c0 = q0, c1 = q1;
    if (jb + 128 < NN) {
      q0 = *(const uint4*)(brow0 + (jb >> 5) + 4);
      q1 = *(const uint4*)(brow1 + (jb >> 5) + 4);
    }
#pragma unroll
    for (int s = 0; s < 4; s++) {
      int j0 = jb + s * 32;
      unsigned wd0 = (s == 0) ? c0.x : (s == 1) ? c0.y : (s == 2) ? c0.z : c0.w;
      unsigned wd1 = (s == 0) ? c1.x : (s == 1) ? c1.y : (s == 2) ? c1.z : c1.w;
      s16x8 cb0 = pb0, cb1 = pb1, cb2 = pb2, cb3 = pb3;
      float4 cfA = pfA, cfB = pfB;
      if (j0 + 32 < NN) {
        const unsigned short* hp = hp_base + j0 + 32;
        pb0 = *(const s16x8*)(hp);
        pb1 = *(const s16x8*)(hp + 16 * NN);
        pb2 = *(const s16x8*)(hp + 32 * NN);
        pb3 = *(const s16x8*)(hp + 48 * NN);
        pfA = *(const float4*)(f2b + j0 + 32);
        pfB = *(const float4*)(f2b + j0 + 36);
      }
      s16x8 af0 = pcompb(fi0, (wd0 >> sh) & 0xffu, cfA, cfB);
      s16x8 af1 = pcompb(fi1, (wd1 >> sh) & 0xffu, cfA, cfB);
      acc[0][0] = __builtin_amdgcn_mfma_f32_16x16x32_bf16(af0, cb0, acc[0][0], 0, 0, 0);
      acc[0][1] = __builtin_amdgcn_mfma_f32_16x16x32_bf16(af0, cb1, acc[0][1], 0, 0, 0);
      acc[0][2] = __builtin_amdgcn_mfma_f32_16x16x32_bf16(af0, cb2, acc[0][2], 0, 0, 0);
      acc[0][3] = __builtin_amdgcn_mfma_f32_16x16x32_bf16(af0, cb3, acc[0][3], 0, 0, 0);
      accs0 = __builtin_amdgcn_mfma_f32_16x16x32_bf16(af0, ones, accs0, 0, 0, 0);
      acc[1][0] = __builtin_amdgcn_mfma_f32_16x16x32_bf16(af1, cb0, acc[1][0], 0, 0, 0);
      acc[1][1] = __builtin_amdgcn_mfma_f32_16x16x32_bf16(af1, cb1, acc[1][1], 0, 0, 0);
      acc[1][2] = __builtin_amdgcn_mfma_f32_16x16x32_bf16(af1, cb2, acc[1][2], 0, 0, 0);
      acc[1][3] = __builtin_amdgcn_mfma_f32_16x16x32_bf16(af1, cb3, acc[1][3], 0, 0, 0);
      accs1 = __builtin_amdgcn_mfma_f32_16x16x32_bf16(af1, ones, accs1, 0, 0, 0);
    }
  }

  // accs[r] = rowsum(row = lg*4 + r), replicated across cols -> no shuffles
  float rd0[4], rd1[4];
#pragma unroll
  for (int r = 0; r < 4; r++) {
    rd0[r] = 1.0f / accs0[r];
    rd1[r] = 1.0f / accs1[r];
  }

#pragma unroll
  for (int nf = 0; nf < 4; nf++)
#pragma unroll
    for (int r = 0; r < 4; r++) {
      int m0 = lg * 4 + r;
      int fcol = f0 + nf * 16 + lr;
      float v0 = acc[0][nf][r] * rd0[r];
      v0 = (v0 > 0.f) ? v0 : expm1f(v0);
      out[((size_t)(b * NN + i0 + m0)) * FOUT + fcol] = v0;
      float v1_ = acc[1][nf][r] * rd1[r];
      v1_ = (v1_ > 0.f) ? v1_ : expm1f(v1_);
      out[((size_t)(b * NN + i0 + 16 + m0)) * FOUT + fcol] = v1_;
    }
}

extern "C" void kernel_launch(void* const* d_in, const int* in_sizes, int n_in,
                              void* d_out, int out_size, void* d_ws, size_t ws_size,
                              hipStream_t stream) {
  const float* inp = (const float*)d_in[0];   // [8][2048][512] f32
  const int* adj   = (const int*)d_in[1];     // [8][2048][2048] i32
  const float* W   = (const float*)d_in[2];   // [512][256] f32
  const float* HT  = (const float*)d_in[3];   // [256][64] f32
  const float* A   = (const float*)d_in[4];   // [128][1] f32
  float* out = (float*)d_out;                 // [8][2048][256] f32

  char* ws = (char*)d_ws;
  float* v1 = (float*)ws;                              // 512 f32
  float* v2 = v1 + 512;                                // 512 f32
  float* f1 = (float*)(ws + 4096);                     // 16384 f32 (x log2e)
  float* f2 = (float*)(ws + 69632);                    // 16384 f32 (x log2e)
  unsigned short* wT = (unsigned short*)(ws + 135168); // 256x512 bf16
  unsigned short* hT = (unsigned short*)(ws + 397312); // 8x256x2048 bf16 -> end 8785920
  unsigned* bits = (unsigned*)(ws + 8785920);          // 8x2048x64 u32  -> end 12980224

  hipLaunchKernelGGL(prep_vecs_k, dim3(128), dim3(256), 0, stream, W, HT, A, v1, v2);
  hipLaunchKernelGGL(prep_wT_k, dim3(512), dim3(256), 0, stream, W, wT);
  hipLaunchKernelGGL(compress_k, dim3(1024), dim3(512), 0, stream, adj, bits);
  hipLaunchKernelGGL(gemm1_k, dim3(256), dim3(512), 0, stream, inp, wT, hT, v1, v2, f1,
                     f2);
  hipLaunchKernelGGL(pv_k, dim3(512), dim3(256), 0, stream, bits, hT, f1, f2, out);
}